// Round 6
// baseline (2661.654 us; speedup 1.0000x reference)
//
#include <hip/hip_runtime.h>

// 2-layer GRU (TF GRUCell) + dense via bf16 MFMA.
// R6: NB=32 (two M=16 tiles per block share every weight fragment -> 2x
// arithmetic intensity, 2x less aggregate L2 weight traffic; 128 blocks).
// XOR-swizzled A-buffers (T2): elem ^= (row&7)<<3, LD multiple of 64 ->
// conflict-free ds_read_b128 A-fragments. LGKM-only barriers (R5) kept.

typedef unsigned short u16;
typedef __attribute__((ext_vector_type(8))) short bhalf8;   // 8 bf16
typedef __attribute__((ext_vector_type(8))) short short8;
typedef __attribute__((ext_vector_type(4))) float fx4;

constexpr int Bc = 4096, Tc = 64, Fc = 32, U1 = 256, U2 = 128;
constexpr int K1 = Fc + U1;   // 288
constexpr int K2 = U1 + U2;   // 384
constexpr int NB = 32, NTHR = 512;
constexpr int NBLK = Bc / NB;  // 128 blocks
constexpr int LD1 = 320;      // multiple of 64 (swizzle-bijective), >= K1
constexpr int LD2 = 384;      // multiple of 64, == K2

// d_ws layout: u16 transposed bf16 weights, then fp32 WdT[32][128].
constexpr int nW1g = K1 * 512, nW1c = K1 * 256, nW2g = K2 * 256, nW2c = K2 * 128;
constexpr int oW1g = 0;
constexpr int oW1c = oW1g + nW1g;
constexpr int oW2g = oW1c + nW1c;
constexpr int oW2c = oW2g + nW2g;
constexpr int WTOT = oW2c + nW2c;   // 368640 u16
constexpr int nWdT = Fc * U2;       // 4096 floats

// dynamic LDS: A1h, A1l [32][LD1]; A2h, A2l [32][LD2]
constexpr int SM_A1 = 32 * LD1;
constexpr int SM_A2 = 32 * LD2;
constexpr int SMEM_U16 = 2 * SM_A1 + 2 * SM_A2;
constexpr size_t SMEM_BYTES = (size_t)SMEM_U16 * 2;   // 90112 B

// LDS-only barrier: waits DS ops, leaves global loads in flight.
#define LGKM_BARRIER() asm volatile("s_waitcnt lgkmcnt(0)\n\ts_barrier" ::: "memory")

__device__ __forceinline__ int swz(int row, int col, int LDA) {
  return row * LDA + (col ^ ((row & 7) << 3));
}

__device__ __forceinline__ u16 bf16_rne(float x) {
  unsigned u = __float_as_uint(x);
  return (u16)((u + 0x7fffu + ((u >> 16) & 1u)) >> 16);
}
__device__ __forceinline__ float bf16_f(u16 h) {
  return __uint_as_float(((unsigned)h) << 16);
}
__device__ __forceinline__ float sigm(float x) { return 1.0f / (1.0f + __expf(-x)); }
__device__ __forceinline__ float tanh_(float x) {
  x = fminf(fmaxf(x, -15.0f), 15.0f);
  const float s = __expf(2.0f * x);
  return (s - 1.0f) / (s + 1.0f);
}

// ---- prep: W[K][N] fp32 -> WT[N][K] bf16; Wd[128][32] -> WdT fp32 ----
__global__ void prep_weights(const float* __restrict__ W1g, const float* __restrict__ W1c,
                             const float* __restrict__ W2g, const float* __restrict__ W2c,
                             const float* __restrict__ Wd, u16* __restrict__ ws) {
  int j = blockIdx.x * 256 + threadIdx.x;
  if (j >= WTOT + nWdT) return;
  if (j >= WTOT) {
    const int jj = j - WTOT;           // jj = o*128 + c
    float* wdT = (float*)(ws + WTOT);
    const int o = jj >> 7, c = jj & 127;
    wdT[jj] = Wd[c * Fc + o];
    return;
  }
  const float* src; u16* dst; int K, N, jj;
  if (j < nW1g)                    { src = W1g; K = K1; N = 512; jj = j;                      dst = ws + oW1g; }
  else if (j < nW1g + nW1c)        { src = W1c; K = K1; N = 256; jj = j - nW1g;               dst = ws + oW1c; }
  else if (j < nW1g + nW1c + nW2g) { src = W2g; K = K2; N = 256; jj = j - nW1g - nW1c;        dst = ws + oW2g; }
  else                             { src = W2c; K = K2; N = 128; jj = j - nW1g - nW1c - nW2g; dst = ws + oW2c; }
  int n = jj / K, k = jj - n * K;
  dst[(size_t)n * K + k] = bf16_rne(src[(size_t)k * N + n]);
}

// Rolling-register weight pipe, consumed by TWO M-tiles (rows lc, lc+16).
template <int NT, int D>
struct Pipe {
  const u16* wp[NT];
  bhalf8 bb[D][NT];
  __device__ __forceinline__ void init(const u16* __restrict__ W, const int* n0,
                                       int K, int lc, int ao) {
#pragma unroll
    for (int i = 0; i < NT; ++i) wp[i] = W + (size_t)(n0[i] + lc) * K + ao;
  }
  __device__ __forceinline__ void prefetch() {
#pragma unroll
    for (int d = 0; d < D; ++d)
#pragma unroll
      for (int i = 0; i < NT; ++i) bb[d][i] = *(const bhalf8*)(wp[i] + d * 32);
  }
  template <int KT, int LDA>
  __device__ __forceinline__ void mm2(fx4 (&acc)[NT][2], const u16* __restrict__ Ah,
                                      const u16* __restrict__ Al, int lc, int ao) {
#pragma unroll
    for (int kt = 0; kt < KT; ++kt) {
      const int c0 = kt * 32 + ao;
      const int cs = c0 ^ ((lc & 7) << 3);            // (lc+16)&7 == lc&7
      const int i0 = lc * LDA + cs;
      const int i1 = (lc + 16) * LDA + cs;
      const bhalf8 ah0 = *(const bhalf8*)&Ah[i0];
      const bhalf8 al0 = *(const bhalf8*)&Al[i0];
      const bhalf8 ah1 = *(const bhalf8*)&Ah[i1];
      const bhalf8 al1 = *(const bhalf8*)&Al[i1];
#pragma unroll
      for (int i = 0; i < NT; ++i) {
        const bhalf8 b = bb[kt % D][i];
        acc[i][0] = __builtin_amdgcn_mfma_f32_16x16x32_bf16(ah0, b, acc[i][0], 0, 0, 0);
        acc[i][0] = __builtin_amdgcn_mfma_f32_16x16x32_bf16(al0, b, acc[i][0], 0, 0, 0);
        acc[i][1] = __builtin_amdgcn_mfma_f32_16x16x32_bf16(ah1, b, acc[i][1], 0, 0, 0);
        acc[i][1] = __builtin_amdgcn_mfma_f32_16x16x32_bf16(al1, b, acc[i][1], 0, 0, 0);
      }
      if (kt + D < KT) {
#pragma unroll
        for (int i = 0; i < NT; ++i) bb[kt % D][i] = *(const bhalf8*)(wp[i] + (kt + D) * 32);
      }
    }
  }
};

__global__ __launch_bounds__(NTHR, 2)
void gru_mfma(const float* __restrict__ frames, const u16* __restrict__ ws,
              const float* __restrict__ b1g, const float* __restrict__ b1c,
              const float* __restrict__ b2g, const float* __restrict__ b2c,
              const float* __restrict__ bd, float* __restrict__ out) {
  extern __shared__ u16 smem[];
  u16* A1h = smem;                 // [32][LD1]  [x | h1 / r*h1]
  u16* A1l = A1h + SM_A1;
  u16* A2h = A1l + SM_A1;          // [32][LD2]  [h1n | h2 / r2*h2]
  u16* A2l = A2h + SM_A2;

  const int tid = threadIdx.x;
  const int w = tid >> 6;          // wave 0..7
  const int l = tid & 63;
  const int lc = l & 15;           // col-in-tile / A row (tile0); tile1 = +16
  const int lk = l >> 4;
  const int ao = lk * 8;
  const int row0 = lk * 4;
  const int b0 = blockIdx.x * NB;

  const float bg1r0 = b1g[w * 32 + lc],       bg1r1 = b1g[w * 32 + 16 + lc];
  const float bg1u0 = b1g[256 + w * 32 + lc], bg1u1 = b1g[256 + w * 32 + 16 + lc];
  const float bc10  = b1c[w * 32 + lc],       bc11  = b1c[w * 32 + 16 + lc];
  const float bg2r  = b2g[w * 16 + lc],       bg2u  = b2g[128 + w * 16 + lc];
  const float bc2v  = b2c[w * 16 + lc];

  Pipe<4, 4> pG1;  Pipe<2, 6> pC1;  Pipe<2, 6> pG2;  Pipe<1, 8> pC2;
  const int n0g1[4] = {w * 32, w * 32 + 16, 256 + w * 32, 256 + w * 32 + 16};
  const int n0c1[2] = {w * 32, w * 32 + 16};
  const int n0g2[2] = {w * 16, 128 + w * 16};
  const int n0c2[1] = {w * 16};
  pG1.init(ws + oW1g, n0g1, K1, lc, ao);
  pC1.init(ws + oW1c, n0c1, K1, lc, ao);
  pG2.init(ws + oW2g, n0g2, K2, lc, ao);
  pC2.init(ws + oW2c, n0c2, K2, lc, ao);

  for (int i = tid; i < SMEM_U16; i += NTHR) smem[i] = 0;

  // x staging: thread stages 2 consecutive features of one batch row
  const int xb = tid >> 4;              // 0..31
  const int xf0 = (tid & 15) * 2;       // 0,2,..,30
  const float* fptr = frames + (size_t)(b0 + xb) * (Tc * Fc) + xf0;

  // prologue: stage x_0, prefetch G1
  {
    const float2 x0 = *(const float2*)(fptr);
    const u16 h0 = bf16_rne(x0.x), h1 = bf16_rne(x0.y);
    const u16 l0 = bf16_rne(x0.x - bf16_f(h0)), l1 = bf16_rne(x0.y - bf16_f(h1));
    const int idx = swz(xb, xf0, LD1);  // even -> 4B aligned
    *(unsigned*)&A1h[idx] = (unsigned)h0 | ((unsigned)h1 << 16);
    *(unsigned*)&A1l[idx] = (unsigned)l0 | ((unsigned)l1 << 16);
  }
  pG1.prefetch();
  LGKM_BARRIER();

  for (int t = 0; t < Tc; ++t) {
    const float2 xn = (t + 1 < Tc) ? *(const float2*)(fptr + (t + 1) * Fc)
                                   : make_float2(0.0f, 0.0f);

    // ---- G1: [x|h1] @ W1g ----
    fx4 a1[4][2] = {
      { {bg1r0, bg1r0, bg1r0, bg1r0}, {bg1r0, bg1r0, bg1r0, bg1r0} },
      { {bg1r1, bg1r1, bg1r1, bg1r1}, {bg1r1, bg1r1, bg1r1, bg1r1} },
      { {bg1u0, bg1u0, bg1u0, bg1u0}, {bg1u0, bg1u0, bg1u0, bg1u0} },
      { {bg1u1, bg1u1, bg1u1, bg1u1}, {bg1u1, bg1u1, bg1u1, bg1u1} } };
    pG1.mm2<9, LD1>(a1, A1h, A1l, lc, ao);
    pC1.prefetch();

    float hold1[2][2][4];   // [m][i][q]; stable until post-B2 writes
#pragma unroll
    for (int m = 0; m < 2; ++m)
#pragma unroll
      for (int i = 0; i < 2; ++i)
#pragma unroll
        for (int q = 0; q < 4; ++q) {
          const int idx = swz(16 * m + row0 + q, Fc + w * 32 + i * 16 + lc, LD1);
          hold1[m][i][q] = bf16_f(A1h[idx]) + bf16_f(A1l[idx]);
        }
    float rr[2][2][4], uu[2][2][4];
#pragma unroll
    for (int m = 0; m < 2; ++m)
#pragma unroll
      for (int i = 0; i < 2; ++i)
#pragma unroll
        for (int q = 0; q < 4; ++q) {
          rr[m][i][q] = sigm(a1[i][m][q]);
          uu[m][i][q] = sigm(a1[2 + i][m][q]);
        }
    LGKM_BARRIER();  // B2: G1 reads of A1 done

#pragma unroll
    for (int m = 0; m < 2; ++m)
#pragma unroll
      for (int i = 0; i < 2; ++i)
#pragma unroll
        for (int q = 0; q < 4; ++q) {
          const int idx = swz(16 * m + row0 + q, Fc + w * 32 + i * 16 + lc, LD1);
          const float rh = rr[m][i][q] * hold1[m][i][q];
          const u16 hh = bf16_rne(rh);
          A1h[idx] = hh;
          A1l[idx] = bf16_rne(rh - bf16_f(hh));
        }
    LGKM_BARRIER();  // B3: r*h1 visible

    // ---- C1: [x|r*h1] @ W1c ----
    fx4 c1a[2][2] = {
      { {bc10, bc10, bc10, bc10}, {bc10, bc10, bc10, bc10} },
      { {bc11, bc11, bc11, bc11}, {bc11, bc11, bc11, bc11} } };
    pC1.mm2<9, LD1>(c1a, A1h, A1l, lc, ao);
    pG2.prefetch();

    u16 hh1[2][2][4], hl1[2][2][4];
#pragma unroll
    for (int m = 0; m < 2; ++m)
#pragma unroll
      for (int i = 0; i < 2; ++i)
#pragma unroll
        for (int q = 0; q < 4; ++q) {
          const float c = tanh_(c1a[i][m][q]);
          const float hn = c + uu[m][i][q] * (hold1[m][i][q] - c);
          hh1[m][i][q] = bf16_rne(hn);
          hl1[m][i][q] = bf16_rne(hn - bf16_f(hh1[m][i][q]));
        }
    LGKM_BARRIER();  // B4: C1 reads of A1 done
#pragma unroll
    for (int m = 0; m < 2; ++m)
#pragma unroll
      for (int i = 0; i < 2; ++i)
#pragma unroll
        for (int q = 0; q < 4; ++q) {
          const int row = 16 * m + row0 + q, col = w * 32 + i * 16 + lc;
          const int idx1 = swz(row, Fc + col, LD1);
          A1h[idx1] = hh1[m][i][q];  A1l[idx1] = hl1[m][i][q];   // h1 for t+1
          const int idx2 = swz(row, col, LD2);
          A2h[idx2] = hh1[m][i][q];  A2l[idx2] = hl1[m][i][q];   // layer2 input
        }
    LGKM_BARRIER();  // B5: h1n visible

    // ---- G2: [h1n|h2] @ W2g ----
    fx4 a2[2][2] = {
      { {bg2r, bg2r, bg2r, bg2r}, {bg2r, bg2r, bg2r, bg2r} },
      { {bg2u, bg2u, bg2u, bg2u}, {bg2u, bg2u, bg2u, bg2u} } };
    pG2.mm2<12, LD2>(a2, A2h, A2l, lc, ao);
    pC2.prefetch();

    float hold2[2][4];
#pragma unroll
    for (int m = 0; m < 2; ++m)
#pragma unroll
      for (int q = 0; q < 4; ++q) {
        const int idx = swz(16 * m + row0 + q, U1 + w * 16 + lc, LD2);
        hold2[m][q] = bf16_f(A2h[idx]) + bf16_f(A2l[idx]);
      }
    float rr2[2][4], uu2[2][4];
#pragma unroll
    for (int m = 0; m < 2; ++m)
#pragma unroll
      for (int q = 0; q < 4; ++q) {
        rr2[m][q] = sigm(a2[0][m][q]);
        uu2[m][q] = sigm(a2[1][m][q]);
      }
    LGKM_BARRIER();  // B6: G2 reads of A2 done

#pragma unroll
    for (int m = 0; m < 2; ++m)
#pragma unroll
      for (int q = 0; q < 4; ++q) {
        const int idx = swz(16 * m + row0 + q, U1 + w * 16 + lc, LD2);
        const float rh = rr2[m][q] * hold2[m][q];
        const u16 hh = bf16_rne(rh);
        A2h[idx] = hh;
        A2l[idx] = bf16_rne(rh - bf16_f(hh));
      }
    LGKM_BARRIER();  // B7: r2*h2 visible

    // ---- C2: [h1n|r2*h2] @ W2c ----
    fx4 c2a[1][2] = { { {bc2v, bc2v, bc2v, bc2v}, {bc2v, bc2v, bc2v, bc2v} } };
    pC2.mm2<12, LD2>(c2a, A2h, A2l, lc, ao);
    pG1.prefetch();            // next step's G1 weights fly across tail barriers
    LGKM_BARRIER();  // B8: C2 reads of A2 done

#pragma unroll
    for (int m = 0; m < 2; ++m)
#pragma unroll
      for (int q = 0; q < 4; ++q) {
        const int idx = swz(16 * m + row0 + q, U1 + w * 16 + lc, LD2);
        const float c = tanh_(c2a[0][m][q]);
        const float hn = c + uu2[m][q] * (hold2[m][q] - c);
        const u16 hh = bf16_rne(hn);
        A2h[idx] = hh;                      // h2 for t+1 (and final out)
        A2l[idx] = bf16_rne(hn - bf16_f(hh));
      }
    // stage x_{t+1} (x-region last read by C1, done at B4)
    {
      const u16 h0 = bf16_rne(xn.x), h1 = bf16_rne(xn.y);
      const u16 l0 = bf16_rne(xn.x - bf16_f(h0)), l1 = bf16_rne(xn.y - bf16_f(h1));
      const int idx = swz(xb, xf0, LD1);
      *(unsigned*)&A1h[idx] = (unsigned)h0 | ((unsigned)h1 << 16);
      *(unsigned*)&A1l[idx] = (unsigned)l0 | ((unsigned)l1 << 16);
    }
    LGKM_BARRIER();  // loop: h2n + x_{t+1} visible
  }

  // ---- dense: out[b][o] = bd[o] + h2[b] . Wd[:,o]  (WdT fp32 in ws) ----
  {
    const float* wdT = (const float*)(ws + WTOT);   // [32][128]
    const int o = tid & 31, bq = tid >> 5;          // rows bq and bq+16
    float accA = bd[o], accB = bd[o];
#pragma unroll 4
    for (int c8 = 0; c8 < 16; ++c8) {
      const int c = c8 * 8;
      const int ia = swz(bq, U1 + c, LD2);
      const int ib = swz(bq + 16, U1 + c, LD2);
      const short8 vhA = *(const short8*)&A2h[ia];
      const short8 vlA = *(const short8*)&A2l[ia];
      const short8 vhB = *(const short8*)&A2h[ib];
      const short8 vlB = *(const short8*)&A2l[ib];
#pragma unroll
      for (int j = 0; j < 8; ++j) {
        const float wv = wdT[o * 128 + c + j];
        accA = fmaf(bf16_f((u16)vhA[j]) + bf16_f((u16)vlA[j]), wv, accA);
        accB = fmaf(bf16_f((u16)vhB[j]) + bf16_f((u16)vlB[j]), wv, accB);
      }
    }
    out[(size_t)(b0 + bq) * Fc + o] = accA;
    out[(size_t)(b0 + bq + 16) * Fc + o] = accB;
  }
}

extern "C" void kernel_launch(void* const* d_in, const int* in_sizes, int n_in,
                              void* d_out, int out_size, void* d_ws, size_t ws_size,
                              hipStream_t stream) {
  const float* frames = (const float*)d_in[0];
  const float* W1g = (const float*)d_in[1];
  const float* b1g = (const float*)d_in[2];
  const float* W1c = (const float*)d_in[3];
  const float* b1c = (const float*)d_in[4];
  const float* W2g = (const float*)d_in[5];
  const float* b2g = (const float*)d_in[6];
  const float* W2c = (const float*)d_in[7];
  const float* b2c = (const float*)d_in[8];
  const float* Wd  = (const float*)d_in[9];
  const float* bd  = (const float*)d_in[10];
  u16* ws = (u16*)d_ws;
  float* outp = (float*)d_out;

  static bool attr_set = false;
  if (!attr_set) {
    hipFuncSetAttribute(reinterpret_cast<const void*>(gru_mfma),
                        hipFuncAttributeMaxDynamicSharedMemorySize, (int)SMEM_BYTES);
    attr_set = true;
  }

  hipLaunchKernelGGL(prep_weights, dim3((WTOT + nWdT + 255) / 256), dim3(256), 0, stream,
                     W1g, W1c, W2g, W2c, Wd, ws);
  hipLaunchKernelGGL(gru_mfma, dim3(NBLK), dim3(NTHR), SMEM_BYTES, stream,
                     frames, ws, b1g, b1c, b2g, b2c, bd, outp);
}

// Round 7
// 2538.794 us; speedup vs baseline: 1.0484x; 1.0484x over previous
//
#include <hip/hip_runtime.h>

// 2-layer GRU (TF GRUCell) + dense via bf16 MFMA.
// R7 = R6 (NB=32, two M=16 tiles share every weight fragment; XOR-swizzled
// A-buffers; LGKM-only barriers) + amdgpu_waves_per_eu(2,2) to force the
// 256-VGPR allocation (R6 spilled at 128 -> 1.4 GB scratch HBM traffic),
// with prefetch depths retuned (G1 D=3, C1/G2 D=6, C2 D=12 full-K).

typedef unsigned short u16;
typedef __attribute__((ext_vector_type(8))) short bhalf8;   // 8 bf16
typedef __attribute__((ext_vector_type(8))) short short8;
typedef __attribute__((ext_vector_type(4))) float fx4;

constexpr int Bc = 4096, Tc = 64, Fc = 32, U1 = 256, U2 = 128;
constexpr int K1 = Fc + U1;   // 288
constexpr int K2 = U1 + U2;   // 384
constexpr int NB = 32, NTHR = 512;
constexpr int NBLK = Bc / NB;  // 128 blocks
constexpr int LD1 = 320;      // multiple of 64 (swizzle-bijective), >= K1
constexpr int LD2 = 384;      // multiple of 64, == K2

// d_ws layout: u16 transposed bf16 weights, then fp32 WdT[32][128].
constexpr int nW1g = K1 * 512, nW1c = K1 * 256, nW2g = K2 * 256, nW2c = K2 * 128;
constexpr int oW1g = 0;
constexpr int oW1c = oW1g + nW1g;
constexpr int oW2g = oW1c + nW1c;
constexpr int oW2c = oW2g + nW2g;
constexpr int WTOT = oW2c + nW2c;   // 368640 u16
constexpr int nWdT = Fc * U2;       // 4096 floats

// dynamic LDS: A1h, A1l [32][LD1]; A2h, A2l [32][LD2]
constexpr int SM_A1 = 32 * LD1;
constexpr int SM_A2 = 32 * LD2;
constexpr int SMEM_U16 = 2 * SM_A1 + 2 * SM_A2;
constexpr size_t SMEM_BYTES = (size_t)SMEM_U16 * 2;   // 90112 B

// LDS-only barrier: waits DS ops, leaves global loads in flight.
#define LGKM_BARRIER() asm volatile("s_waitcnt lgkmcnt(0)\n\ts_barrier" ::: "memory")

__device__ __forceinline__ int swz(int row, int col, int LDA) {
  return row * LDA + (col ^ ((row & 7) << 3));
}

__device__ __forceinline__ u16 bf16_rne(float x) {
  unsigned u = __float_as_uint(x);
  return (u16)((u + 0x7fffu + ((u >> 16) & 1u)) >> 16);
}
__device__ __forceinline__ float bf16_f(u16 h) {
  return __uint_as_float(((unsigned)h) << 16);
}
__device__ __forceinline__ float sigm(float x) { return 1.0f / (1.0f + __expf(-x)); }
__device__ __forceinline__ float tanh_(float x) {
  x = fminf(fmaxf(x, -15.0f), 15.0f);
  const float s = __expf(2.0f * x);
  return (s - 1.0f) / (s + 1.0f);
}

// ---- prep: W[K][N] fp32 -> WT[N][K] bf16; Wd[128][32] -> WdT fp32 ----
__global__ void prep_weights(const float* __restrict__ W1g, const float* __restrict__ W1c,
                             const float* __restrict__ W2g, const float* __restrict__ W2c,
                             const float* __restrict__ Wd, u16* __restrict__ ws) {
  int j = blockIdx.x * 256 + threadIdx.x;
  if (j >= WTOT + nWdT) return;
  if (j >= WTOT) {
    const int jj = j - WTOT;           // jj = o*128 + c
    float* wdT = (float*)(ws + WTOT);
    const int o = jj >> 7, c = jj & 127;
    wdT[jj] = Wd[c * Fc + o];
    return;
  }
  const float* src; u16* dst; int K, N, jj;
  if (j < nW1g)                    { src = W1g; K = K1; N = 512; jj = j;                      dst = ws + oW1g; }
  else if (j < nW1g + nW1c)        { src = W1c; K = K1; N = 256; jj = j - nW1g;               dst = ws + oW1c; }
  else if (j < nW1g + nW1c + nW2g) { src = W2g; K = K2; N = 256; jj = j - nW1g - nW1c;        dst = ws + oW2g; }
  else                             { src = W2c; K = K2; N = 128; jj = j - nW1g - nW1c - nW2g; dst = ws + oW2c; }
  int n = jj / K, k = jj - n * K;
  dst[(size_t)n * K + k] = bf16_rne(src[(size_t)k * N + n]);
}

// Rolling-register weight pipe, consumed by TWO M-tiles (rows lc, lc+16).
template <int NT, int D>
struct Pipe {
  const u16* wp[NT];
  bhalf8 bb[D][NT];
  __device__ __forceinline__ void init(const u16* __restrict__ W, const int* n0,
                                       int K, int lc, int ao) {
#pragma unroll
    for (int i = 0; i < NT; ++i) wp[i] = W + (size_t)(n0[i] + lc) * K + ao;
  }
  __device__ __forceinline__ void prefetch() {
#pragma unroll
    for (int d = 0; d < D; ++d)
#pragma unroll
      for (int i = 0; i < NT; ++i) bb[d][i] = *(const bhalf8*)(wp[i] + d * 32);
  }
  template <int KT, int LDA>
  __device__ __forceinline__ void mm2(fx4 (&acc)[NT][2], const u16* __restrict__ Ah,
                                      const u16* __restrict__ Al, int lc, int ao) {
#pragma unroll
    for (int kt = 0; kt < KT; ++kt) {
      const int c0 = kt * 32 + ao;
      const int cs = c0 ^ ((lc & 7) << 3);            // (lc+16)&7 == lc&7
      const int i0 = lc * LDA + cs;
      const int i1 = (lc + 16) * LDA + cs;
      const bhalf8 ah0 = *(const bhalf8*)&Ah[i0];
      const bhalf8 al0 = *(const bhalf8*)&Al[i0];
      const bhalf8 ah1 = *(const bhalf8*)&Ah[i1];
      const bhalf8 al1 = *(const bhalf8*)&Al[i1];
#pragma unroll
      for (int i = 0; i < NT; ++i) {
        const bhalf8 b = bb[kt % D][i];
        acc[i][0] = __builtin_amdgcn_mfma_f32_16x16x32_bf16(ah0, b, acc[i][0], 0, 0, 0);
        acc[i][0] = __builtin_amdgcn_mfma_f32_16x16x32_bf16(al0, b, acc[i][0], 0, 0, 0);
        acc[i][1] = __builtin_amdgcn_mfma_f32_16x16x32_bf16(ah1, b, acc[i][1], 0, 0, 0);
        acc[i][1] = __builtin_amdgcn_mfma_f32_16x16x32_bf16(al1, b, acc[i][1], 0, 0, 0);
      }
      if (kt + D < KT) {
#pragma unroll
        for (int i = 0; i < NT; ++i) bb[kt % D][i] = *(const bhalf8*)(wp[i] + (kt + D) * 32);
      }
    }
  }
};

__global__ __attribute__((amdgpu_flat_work_group_size(NTHR, NTHR), amdgpu_waves_per_eu(2, 2)))
void gru_mfma(const float* __restrict__ frames, const u16* __restrict__ ws,
              const float* __restrict__ b1g, const float* __restrict__ b1c,
              const float* __restrict__ b2g, const float* __restrict__ b2c,
              const float* __restrict__ bd, float* __restrict__ out) {
  extern __shared__ u16 smem[];
  u16* A1h = smem;                 // [32][LD1]  [x | h1 / r*h1]
  u16* A1l = A1h + SM_A1;
  u16* A2h = A1l + SM_A1;          // [32][LD2]  [h1n | h2 / r2*h2]
  u16* A2l = A2h + SM_A2;

  const int tid = threadIdx.x;
  const int w = tid >> 6;          // wave 0..7
  const int l = tid & 63;
  const int lc = l & 15;           // col-in-tile / A row (tile0); tile1 = +16
  const int lk = l >> 4;
  const int ao = lk * 8;
  const int row0 = lk * 4;
  const int b0 = blockIdx.x * NB;

  const float bg1r0 = b1g[w * 32 + lc],       bg1r1 = b1g[w * 32 + 16 + lc];
  const float bg1u0 = b1g[256 + w * 32 + lc], bg1u1 = b1g[256 + w * 32 + 16 + lc];
  const float bc10  = b1c[w * 32 + lc],       bc11  = b1c[w * 32 + 16 + lc];
  const float bg2r  = b2g[w * 16 + lc],       bg2u  = b2g[128 + w * 16 + lc];
  const float bc2v  = b2c[w * 16 + lc];

  Pipe<4, 3> pG1;  Pipe<2, 6> pC1;  Pipe<2, 6> pG2;  Pipe<1, 12> pC2;
  const int n0g1[4] = {w * 32, w * 32 + 16, 256 + w * 32, 256 + w * 32 + 16};
  const int n0c1[2] = {w * 32, w * 32 + 16};
  const int n0g2[2] = {w * 16, 128 + w * 16};
  const int n0c2[1] = {w * 16};
  pG1.init(ws + oW1g, n0g1, K1, lc, ao);
  pC1.init(ws + oW1c, n0c1, K1, lc, ao);
  pG2.init(ws + oW2g, n0g2, K2, lc, ao);
  pC2.init(ws + oW2c, n0c2, K2, lc, ao);

  for (int i = tid; i < SMEM_U16; i += NTHR) smem[i] = 0;

  // x staging: thread stages 2 consecutive features of one batch row
  const int xb = tid >> 4;              // 0..31
  const int xf0 = (tid & 15) * 2;       // 0,2,..,30
  const float* fptr = frames + (size_t)(b0 + xb) * (Tc * Fc) + xf0;

  // prologue: stage x_0, prefetch G1
  {
    const float2 x0 = *(const float2*)(fptr);
    const u16 h0 = bf16_rne(x0.x), h1 = bf16_rne(x0.y);
    const u16 l0 = bf16_rne(x0.x - bf16_f(h0)), l1 = bf16_rne(x0.y - bf16_f(h1));
    const int idx = swz(xb, xf0, LD1);  // even -> 4B aligned
    *(unsigned*)&A1h[idx] = (unsigned)h0 | ((unsigned)h1 << 16);
    *(unsigned*)&A1l[idx] = (unsigned)l0 | ((unsigned)l1 << 16);
  }
  pG1.prefetch();
  LGKM_BARRIER();

  for (int t = 0; t < Tc; ++t) {
    const float2 xn = (t + 1 < Tc) ? *(const float2*)(fptr + (t + 1) * Fc)
                                   : make_float2(0.0f, 0.0f);

    // ---- G1: [x|h1] @ W1g ----
    fx4 a1[4][2] = {
      { {bg1r0, bg1r0, bg1r0, bg1r0}, {bg1r0, bg1r0, bg1r0, bg1r0} },
      { {bg1r1, bg1r1, bg1r1, bg1r1}, {bg1r1, bg1r1, bg1r1, bg1r1} },
      { {bg1u0, bg1u0, bg1u0, bg1u0}, {bg1u0, bg1u0, bg1u0, bg1u0} },
      { {bg1u1, bg1u1, bg1u1, bg1u1}, {bg1u1, bg1u1, bg1u1, bg1u1} } };
    pG1.mm2<9, LD1>(a1, A1h, A1l, lc, ao);
    pC1.prefetch();

    float hold1[2][2][4];   // [m][i][q]; stable until post-B2 writes
#pragma unroll
    for (int m = 0; m < 2; ++m)
#pragma unroll
      for (int i = 0; i < 2; ++i)
#pragma unroll
        for (int q = 0; q < 4; ++q) {
          const int idx = swz(16 * m + row0 + q, Fc + w * 32 + i * 16 + lc, LD1);
          hold1[m][i][q] = bf16_f(A1h[idx]) + bf16_f(A1l[idx]);
        }
    float rr[2][2][4], uu[2][2][4];
#pragma unroll
    for (int m = 0; m < 2; ++m)
#pragma unroll
      for (int i = 0; i < 2; ++i)
#pragma unroll
        for (int q = 0; q < 4; ++q) {
          rr[m][i][q] = sigm(a1[i][m][q]);
          uu[m][i][q] = sigm(a1[2 + i][m][q]);
        }
    LGKM_BARRIER();  // B2: G1 reads of A1 done

#pragma unroll
    for (int m = 0; m < 2; ++m)
#pragma unroll
      for (int i = 0; i < 2; ++i)
#pragma unroll
        for (int q = 0; q < 4; ++q) {
          const int idx = swz(16 * m + row0 + q, Fc + w * 32 + i * 16 + lc, LD1);
          const float rh = rr[m][i][q] * hold1[m][i][q];
          const u16 hh = bf16_rne(rh);
          A1h[idx] = hh;
          A1l[idx] = bf16_rne(rh - bf16_f(hh));
        }
    LGKM_BARRIER();  // B3: r*h1 visible

    // ---- C1: [x|r*h1] @ W1c ----
    fx4 c1a[2][2] = {
      { {bc10, bc10, bc10, bc10}, {bc10, bc10, bc10, bc10} },
      { {bc11, bc11, bc11, bc11}, {bc11, bc11, bc11, bc11} } };
    pC1.mm2<9, LD1>(c1a, A1h, A1l, lc, ao);
    pG2.prefetch();

    u16 hh1[2][2][4], hl1[2][2][4];
#pragma unroll
    for (int m = 0; m < 2; ++m)
#pragma unroll
      for (int i = 0; i < 2; ++i)
#pragma unroll
        for (int q = 0; q < 4; ++q) {
          const float c = tanh_(c1a[i][m][q]);
          const float hn = c + uu[m][i][q] * (hold1[m][i][q] - c);
          hh1[m][i][q] = bf16_rne(hn);
          hl1[m][i][q] = bf16_rne(hn - bf16_f(hh1[m][i][q]));
        }
    LGKM_BARRIER();  // B4: C1 reads of A1 done
#pragma unroll
    for (int m = 0; m < 2; ++m)
#pragma unroll
      for (int i = 0; i < 2; ++i)
#pragma unroll
        for (int q = 0; q < 4; ++q) {
          const int row = 16 * m + row0 + q, col = w * 32 + i * 16 + lc;
          const int idx1 = swz(row, Fc + col, LD1);
          A1h[idx1] = hh1[m][i][q];  A1l[idx1] = hl1[m][i][q];   // h1 for t+1
          const int idx2 = swz(row, col, LD2);
          A2h[idx2] = hh1[m][i][q];  A2l[idx2] = hl1[m][i][q];   // layer2 input
        }
    LGKM_BARRIER();  // B5: h1n visible

    // ---- G2: [h1n|h2] @ W2g ----
    fx4 a2[2][2] = {
      { {bg2r, bg2r, bg2r, bg2r}, {bg2r, bg2r, bg2r, bg2r} },
      { {bg2u, bg2u, bg2u, bg2u}, {bg2u, bg2u, bg2u, bg2u} } };
    pG2.mm2<12, LD2>(a2, A2h, A2l, lc, ao);
    pC2.prefetch();

    float hold2[2][4];
#pragma unroll
    for (int m = 0; m < 2; ++m)
#pragma unroll
      for (int q = 0; q < 4; ++q) {
        const int idx = swz(16 * m + row0 + q, U1 + w * 16 + lc, LD2);
        hold2[m][q] = bf16_f(A2h[idx]) + bf16_f(A2l[idx]);
      }
    float rr2[2][4], uu2[2][4];
#pragma unroll
    for (int m = 0; m < 2; ++m)
#pragma unroll
      for (int q = 0; q < 4; ++q) {
        rr2[m][q] = sigm(a2[0][m][q]);
        uu2[m][q] = sigm(a2[1][m][q]);
      }
    LGKM_BARRIER();  // B6: G2 reads of A2 done

#pragma unroll
    for (int m = 0; m < 2; ++m)
#pragma unroll
      for (int q = 0; q < 4; ++q) {
        const int idx = swz(16 * m + row0 + q, U1 + w * 16 + lc, LD2);
        const float rh = rr2[m][q] * hold2[m][q];
        const u16 hh = bf16_rne(rh);
        A2h[idx] = hh;
        A2l[idx] = bf16_rne(rh - bf16_f(hh));
      }
    LGKM_BARRIER();  // B7: r2*h2 visible

    // ---- C2: [h1n|r2*h2] @ W2c ----
    fx4 c2a[1][2] = { { {bc2v, bc2v, bc2v, bc2v}, {bc2v, bc2v, bc2v, bc2v} } };
    pC2.mm2<12, LD2>(c2a, A2h, A2l, lc, ao);
    pG1.prefetch();            // next step's G1 weights fly across tail barriers
    LGKM_BARRIER();  // B8: C2 reads of A2 done

#pragma unroll
    for (int m = 0; m < 2; ++m)
#pragma unroll
      for (int q = 0; q < 4; ++q) {
        const int idx = swz(16 * m + row0 + q, U1 + w * 16 + lc, LD2);
        const float c = tanh_(c2a[0][m][q]);
        const float hn = c + uu2[m][q] * (hold2[m][q] - c);
        const u16 hh = bf16_rne(hn);
        A2h[idx] = hh;                      // h2 for t+1 (and final out)
        A2l[idx] = bf16_rne(hn - bf16_f(hh));
      }
    // stage x_{t+1} (x-region last read by C1, done at B4)
    {
      const u16 h0 = bf16_rne(xn.x), h1 = bf16_rne(xn.y);
      const u16 l0 = bf16_rne(xn.x - bf16_f(h0)), l1 = bf16_rne(xn.y - bf16_f(h1));
      const int idx = swz(xb, xf0, LD1);
      *(unsigned*)&A1h[idx] = (unsigned)h0 | ((unsigned)h1 << 16);
      *(unsigned*)&A1l[idx] = (unsigned)l0 | ((unsigned)l1 << 16);
    }
    LGKM_BARRIER();  // loop: h2n + x_{t+1} visible
  }

  // ---- dense: out[b][o] = bd[o] + h2[b] . Wd[:,o]  (WdT fp32 in ws) ----
  {
    const float* wdT = (const float*)(ws + WTOT);   // [32][128]
    const int o = tid & 31, bq = tid >> 5;          // rows bq and bq+16
    float accA = bd[o], accB = bd[o];
#pragma unroll 4
    for (int c8 = 0; c8 < 16; ++c8) {
      const int c = c8 * 8;
      const int ia = swz(bq, U1 + c, LD2);
      const int ib = swz(bq + 16, U1 + c, LD2);
      const short8 vhA = *(const short8*)&A2h[ia];
      const short8 vlA = *(const short8*)&A2l[ia];
      const short8 vhB = *(const short8*)&A2h[ib];
      const short8 vlB = *(const short8*)&A2l[ib];
#pragma unroll
      for (int j = 0; j < 8; ++j) {
        const float wv = wdT[o * 128 + c + j];
        accA = fmaf(bf16_f((u16)vhA[j]) + bf16_f((u16)vlA[j]), wv, accA);
        accB = fmaf(bf16_f((u16)vhB[j]) + bf16_f((u16)vlB[j]), wv, accB);
      }
    }
    out[(size_t)(b0 + bq) * Fc + o] = accA;
    out[(size_t)(b0 + bq + 16) * Fc + o] = accB;
  }
}

extern "C" void kernel_launch(void* const* d_in, const int* in_sizes, int n_in,
                              void* d_out, int out_size, void* d_ws, size_t ws_size,
                              hipStream_t stream) {
  const float* frames = (const float*)d_in[0];
  const float* W1g = (const float*)d_in[1];
  const float* b1g = (const float*)d_in[2];
  const float* W1c = (const float*)d_in[3];
  const float* b1c = (const float*)d_in[4];
  const float* W2g = (const float*)d_in[5];
  const float* b2g = (const float*)d_in[6];
  const float* W2c = (const float*)d_in[7];
  const float* b2c = (const float*)d_in[8];
  const float* Wd  = (const float*)d_in[9];
  const float* bd  = (const float*)d_in[10];
  u16* ws = (u16*)d_ws;
  float* outp = (float*)d_out;

  static bool attr_set = false;
  if (!attr_set) {
    hipFuncSetAttribute(reinterpret_cast<const void*>(gru_mfma),
                        hipFuncAttributeMaxDynamicSharedMemorySize, (int)SMEM_BYTES);
    attr_set = true;
  }

  hipLaunchKernelGGL(prep_weights, dim3((WTOT + nWdT + 255) / 256), dim3(256), 0, stream,
                     W1g, W1c, W2g, W2c, Wd, ws);
  hipLaunchKernelGGL(gru_mfma, dim3(NBLK), dim3(NTHR), SMEM_BYTES, stream,
                     frames, ws, b1g, b1c, b2g, b2c, bd, outp);
}

// Round 8
// 2147.950 us; speedup vs baseline: 1.2392x; 1.1820x over previous
//
#include <hip/hip_runtime.h>

// 2-layer GRU (TF GRUCell) + dense via bf16 MFMA, NB=32 with 32x32x16 MFMA.
// R8: register-budget-engineered NB=32 (R6/R7 spilled ~400 VGPRs):
//  - mfma_f32_32x32x16_bf16: one 32-row tile per wave-column-group ->
//    single fx16 acc, single A-frag, NT halved -> pipes 4x smaller.
//  - h1 state lives ONLY in A2 (G1/C1 read x from tiny A1x for k<32).
//  - layer2 wave roles: waves 0-3 own u2+c2 cols (u2 in regs), waves 4-7 own
//    r2 cols (write r2*h2). No staging buffers.
//  - LGKM-only barriers keep the weight stream in flight across barriers.

typedef unsigned short u16;
typedef __attribute__((ext_vector_type(8))) short bhalf8;   // 8 bf16
typedef __attribute__((ext_vector_type(8))) short short8;
typedef __attribute__((ext_vector_type(16))) float fx16;

constexpr int Bc = 4096, Tc = 64, Fc = 32, U1 = 256, U2 = 128;
constexpr int K1 = Fc + U1;   // 288
constexpr int K2 = U1 + U2;   // 384
constexpr int NB = 32, NTHR = 512;
constexpr int NBLK = Bc / NB;  // 128 blocks
constexpr int LDX = 40;        // A1x row stride (u16)
constexpr int LD2 = 384;       // A2 row stride (u16), multiple of 64

// d_ws layout: u16 transposed bf16 weights, then fp32 WdT[32][128].
constexpr int nW1g = K1 * 512, nW1c = K1 * 256, nW2g = K2 * 256, nW2c = K2 * 128;
constexpr int oW1g = 0;
constexpr int oW1c = oW1g + nW1g;
constexpr int oW2g = oW1c + nW1c;
constexpr int oW2c = oW2g + nW2g;
constexpr int WTOT = oW2c + nW2c;   // 368640 u16 (byte offset 737280, 16B-aligned)
constexpr int nWdT = Fc * U2;       // 4096 floats

// LDS-only barrier: waits DS ops, leaves global loads in flight.
#define LGKM_BARRIER() asm volatile("s_waitcnt lgkmcnt(0)\n\ts_barrier" ::: "memory")

__device__ __forceinline__ u16 bf16_rne(float x) {
  unsigned u = __float_as_uint(x);
  return (u16)((u + 0x7fffu + ((u >> 16) & 1u)) >> 16);
}
__device__ __forceinline__ float bf16_f(u16 h) {
  return __uint_as_float(((unsigned)h) << 16);
}
__device__ __forceinline__ float sigm(float x) { return 1.0f / (1.0f + __expf(-x)); }
__device__ __forceinline__ float tanh_(float x) {
  x = fminf(fmaxf(x, -15.0f), 15.0f);
  const float s = __expf(2.0f * x);
  return (s - 1.0f) / (s + 1.0f);
}

// ---- prep: W[K][N] fp32 -> WT[N][K] bf16; Wd[128][32] -> WdT fp32 ----
__global__ void prep_weights(const float* __restrict__ W1g, const float* __restrict__ W1c,
                             const float* __restrict__ W2g, const float* __restrict__ W2c,
                             const float* __restrict__ Wd, u16* __restrict__ ws) {
  int j = blockIdx.x * 256 + threadIdx.x;
  if (j >= WTOT + nWdT) return;
  if (j >= WTOT) {
    const int jj = j - WTOT;           // jj = o*128 + c
    float* wdT = (float*)(ws + WTOT);
    const int o = jj >> 7, c = jj & 127;
    wdT[jj] = Wd[c * Fc + o];
    return;
  }
  const float* src; u16* dst; int K, N, jj;
  if (j < nW1g)                    { src = W1g; K = K1; N = 512; jj = j;                      dst = ws + oW1g; }
  else if (j < nW1g + nW1c)        { src = W1c; K = K1; N = 256; jj = j - nW1g;               dst = ws + oW1c; }
  else if (j < nW1g + nW1c + nW2g) { src = W2g; K = K2; N = 256; jj = j - nW1g - nW1c;        dst = ws + oW2g; }
  else                             { src = W2c; K = K2; N = 128; jj = j - nW1g - nW1c - nW2g; dst = ws + oW2c; }
  int n = jj / K, k = jj - n * K;
  dst[(size_t)n * K + k] = bf16_rne(src[(size_t)k * N + n]);
}

// Rolling-register weight pipe; unit = one K=16 half (16B/lane B-fragment).
template <int NT, int D, int KH>
struct Pipe {
  const u16* wp[NT];
  bhalf8 bb[D][NT];
  __device__ __forceinline__ void init(const u16* __restrict__ W, const int* n0,
                                       int K, int cl, int ko) {
#pragma unroll
    for (int i = 0; i < NT; ++i) wp[i] = W + (size_t)(n0[i] + cl) * K + ko;
  }
  __device__ __forceinline__ void prefetch() {
#pragma unroll
    for (int d = 0; d < D; ++d)
#pragma unroll
      for (int i = 0; i < NT; ++i) bb[d][i] = *(const bhalf8*)(wp[i] + d * 16);
  }
  __device__ __forceinline__ void roll(int kh) {
    if (kh + D < KH) {
#pragma unroll
      for (int i = 0; i < NT; ++i) bb[kh % D][i] = *(const bhalf8*)(wp[i] + (kh + D) * 16);
    }
  }
};

__global__ __launch_bounds__(NTHR, 1)
void gru_mfma(const float* __restrict__ frames, const u16* __restrict__ ws,
              const float* __restrict__ b1g, const float* __restrict__ b1c,
              const float* __restrict__ b2g, const float* __restrict__ b2c,
              const float* __restrict__ bd, float* __restrict__ out) {
  // A2: [32][LD2]; cols 0..255 = h1 / r*h1 / h1n; cols 256..383 = h2 / r2*h2 / h2n
  __shared__ alignas(16) u16 A2h_s[32 * LD2], A2l_s[32 * LD2];
  __shared__ alignas(16) u16 A1xh[32 * LDX], A1xl[32 * LDX];   // x_t hi/lo

  const int tid = threadIdx.x;
  const int w = tid >> 6;          // wave 0..7
  const int l = tid & 63;
  const int cl = l & 31;           // A row / output col within tile
  const int hi = l >> 5;
  const int ko = hi * 8;           // per-lane K offset within a K=16 half
  const int b0 = blockIdx.x * NB;

  // elementwise rows for 32x32 C layout: row = (reg&3) + 8*(reg>>2) + 4*hi
  const int col1 = w * 32 + cl;                 // layer1 output col (0..255)
  const int w2 = (w < 4) ? w : (w - 4);
  const int col2 = w2 * 32 + cl;                // layer2 col (0..127)

  const float bR  = b1g[col1];
  const float bU  = b1g[256 + col1];
  const float bC1 = b1c[col1];
  const float bG2 = (w < 4) ? b2g[128 + col2] : b2g[col2];   // u2 : r2
  const float bC2 = b2c[col2];

  Pipe<2, 4, 18> pG1;  Pipe<1, 6, 18> pC1;  Pipe<1, 6, 24> pG2;  Pipe<1, 6, 24> pC2;
  const int n0g1[2] = {w * 32, 256 + w * 32};
  const int n0c1[1] = {w * 32};
  const int n0g2[1] = {(w < 4) ? (128 + w * 32) : ((w - 4) * 32)};
  const int n0c2[1] = {w2 * 32};
  pG1.init(ws + oW1g, n0g1, K1, cl, ko);
  pC1.init(ws + oW1c, n0c1, K1, cl, ko);
  pG2.init(ws + oW2g, n0g2, K2, cl, ko);
  pC2.init(ws + oW2c, n0c2, K2, cl, ko);

  for (int i = tid; i < 32 * LD2; i += NTHR) { A2h_s[i] = 0; A2l_s[i] = 0; }
  for (int i = tid; i < 32 * LDX; i += NTHR) { A1xh[i] = 0; A1xl[i] = 0; }

  // x staging: thread stages 2 consecutive features of one batch row
  const int xb = tid >> 4;              // 0..31
  const int xf0 = (tid & 15) * 2;       // 0,2,..,30
  const float* fptr = frames + (size_t)(b0 + xb) * (Tc * Fc) + xf0;

  {
    const float2 x0 = *(const float2*)(fptr);
    const u16 h0 = bf16_rne(x0.x), h1v = bf16_rne(x0.y);
    const u16 l0 = bf16_rne(x0.x - bf16_f(h0)), l1v = bf16_rne(x0.y - bf16_f(h1v));
    const int idx = xb * LDX + xf0;
    *(unsigned*)&A1xh[idx] = (unsigned)h0 | ((unsigned)h1v << 16);
    *(unsigned*)&A1xl[idx] = (unsigned)l0 | ((unsigned)l1v << 16);
  }
  pG1.prefetch();
  LGKM_BARRIER();

  // A-fragment loaders (row = cl). Layer1 K-space: [x(32) | A2 cols 0..255].
  auto ldA1 = [&](int kh, bhalf8& ah, bhalf8& al) {
    if (kh < 2) {
      const int idx = cl * LDX + kh * 16 + ko;
      ah = *(const bhalf8*)&A1xh[idx];
      al = *(const bhalf8*)&A1xl[idx];
    } else {
      const int c = kh * 16 - 32 + ko;
      const int idx = cl * LD2 + (c ^ ((cl & 7) << 3));
      ah = *(const bhalf8*)&A2h_s[idx];
      al = *(const bhalf8*)&A2l_s[idx];
    }
  };
  auto ldA2 = [&](int kh, bhalf8& ah, bhalf8& al) {   // layer2: A2 cols 0..383
    const int c = kh * 16 + ko;
    const int idx = cl * LD2 + (c ^ ((cl & 7) << 3));
    ah = *(const bhalf8*)&A2h_s[idx];
    al = *(const bhalf8*)&A2l_s[idx];
  };
  auto ew = [&](int row, int col) { return row * LD2 + (col ^ ((row & 7) << 3)); };

  for (int t = 0; t < Tc; ++t) {
    const float2 xn = (t + 1 < Tc) ? *(const float2*)(fptr + (t + 1) * Fc)
                                   : make_float2(0.0f, 0.0f);

    // ---- G1: [x|h1] @ W1g -> r (tile0), u (tile1) ----
    fx16 aR, aU;
#pragma unroll
    for (int j = 0; j < 16; ++j) { aR[j] = bR; aU[j] = bU; }
#pragma unroll
    for (int kh = 0; kh < 18; ++kh) {
      bhalf8 ah, al; ldA1(kh, ah, al);
      aR = __builtin_amdgcn_mfma_f32_32x32x16_bf16(ah, pG1.bb[kh % 4][0], aR, 0, 0, 0);
      aR = __builtin_amdgcn_mfma_f32_32x32x16_bf16(al, pG1.bb[kh % 4][0], aR, 0, 0, 0);
      aU = __builtin_amdgcn_mfma_f32_32x32x16_bf16(ah, pG1.bb[kh % 4][1], aU, 0, 0, 0);
      aU = __builtin_amdgcn_mfma_f32_32x32x16_bf16(al, pG1.bb[kh % 4][1], aU, 0, 0, 0);
      pG1.roll(kh);
    }
    pC1.prefetch();

    float hold1[16], rr[16], uu[16];
#pragma unroll
    for (int j = 0; j < 16; ++j) {
      const int row = (j & 3) + 8 * (j >> 2) + 4 * hi;
      const int idx = ew(row, col1);
      hold1[j] = bf16_f(A2h_s[idx]) + bf16_f(A2l_s[idx]);
      rr[j] = sigm(aR[j]);
      uu[j] = sigm(aU[j]);
    }
    LGKM_BARRIER();  // B2: G1 reads of A2/A1x done
#pragma unroll
    for (int j = 0; j < 16; ++j) {
      const int row = (j & 3) + 8 * (j >> 2) + 4 * hi;
      const int idx = ew(row, col1);
      const float rh = rr[j] * hold1[j];
      const u16 hh = bf16_rne(rh);
      A2h_s[idx] = hh;
      A2l_s[idx] = bf16_rne(rh - bf16_f(hh));
    }
    LGKM_BARRIER();  // B3: r*h1 visible

    // ---- C1: [x|r*h1] @ W1c ----
    fx16 aC;
#pragma unroll
    for (int j = 0; j < 16; ++j) aC[j] = bC1;
#pragma unroll
    for (int kh = 0; kh < 18; ++kh) {
      bhalf8 ah, al; ldA1(kh, ah, al);
      aC = __builtin_amdgcn_mfma_f32_32x32x16_bf16(ah, pC1.bb[kh % 6][0], aC, 0, 0, 0);
      aC = __builtin_amdgcn_mfma_f32_32x32x16_bf16(al, pC1.bb[kh % 6][0], aC, 0, 0, 0);
      pC1.roll(kh);
    }
    pG2.prefetch();

    u16 hh1[16], hl1[16];
#pragma unroll
    for (int j = 0; j < 16; ++j) {
      const float c = tanh_(aC[j]);
      const float hn = c + uu[j] * (hold1[j] - c);
      hh1[j] = bf16_rne(hn);
      hl1[j] = bf16_rne(hn - bf16_f(hh1[j]));
    }
    LGKM_BARRIER();  // B4: C1 reads of A2/A1x done
#pragma unroll
    for (int j = 0; j < 16; ++j) {
      const int row = (j & 3) + 8 * (j >> 2) + 4 * hi;
      const int idx = ew(row, col1);
      A2h_s[idx] = hh1[j];
      A2l_s[idx] = hl1[j];
    }
    // stage x_{t+1} (A1x last read by C1)
    {
      const u16 h0 = bf16_rne(xn.x), h1v = bf16_rne(xn.y);
      const u16 l0 = bf16_rne(xn.x - bf16_f(h0)), l1v = bf16_rne(xn.y - bf16_f(h1v));
      const int idx = xb * LDX + xf0;
      *(unsigned*)&A1xh[idx] = (unsigned)h0 | ((unsigned)h1v << 16);
      *(unsigned*)&A1xl[idx] = (unsigned)l0 | ((unsigned)l1v << 16);
    }
    LGKM_BARRIER();  // B5: h1n + x_{t+1} visible

    // ---- G2: [h1n|h2] @ W2g -> waves 0-3: u2; waves 4-7: r2 ----
    fx16 a2;
#pragma unroll
    for (int j = 0; j < 16; ++j) a2[j] = bG2;
#pragma unroll
    for (int kh = 0; kh < 24; ++kh) {
      bhalf8 ah, al; ldA2(kh, ah, al);
      a2 = __builtin_amdgcn_mfma_f32_32x32x16_bf16(ah, pG2.bb[kh % 6][0], a2, 0, 0, 0);
      a2 = __builtin_amdgcn_mfma_f32_32x32x16_bf16(al, pG2.bb[kh % 6][0], a2, 0, 0, 0);
      pG2.roll(kh);
    }
    if (w < 4) pC2.prefetch();

    float hold2[16], g2v[16];
#pragma unroll
    for (int j = 0; j < 16; ++j) {
      const int row = (j & 3) + 8 * (j >> 2) + 4 * hi;
      const int idx = ew(row, 256 + col2);
      hold2[j] = bf16_f(A2h_s[idx]) + bf16_f(A2l_s[idx]);
      g2v[j] = sigm(a2[j]);
    }
    LGKM_BARRIER();  // B6: G2 reads of A2 done
    if (w >= 4) {
#pragma unroll
      for (int j = 0; j < 16; ++j) {
        const int row = (j & 3) + 8 * (j >> 2) + 4 * hi;
        const int idx = ew(row, 256 + col2);
        const float rh = g2v[j] * hold2[j];
        const u16 hh = bf16_rne(rh);
        A2h_s[idx] = hh;
        A2l_s[idx] = bf16_rne(rh - bf16_f(hh));
      }
    }
    LGKM_BARRIER();  // B7: r2*h2 visible

    // ---- C2: [h1n|r2*h2] @ W2c (waves 0-3) ----
    fx16 aC2;
#pragma unroll
    for (int j = 0; j < 16; ++j) aC2[j] = bC2;
    if (w < 4) {
#pragma unroll
      for (int kh = 0; kh < 24; ++kh) {
        bhalf8 ah, al; ldA2(kh, ah, al);
        aC2 = __builtin_amdgcn_mfma_f32_32x32x16_bf16(ah, pC2.bb[kh % 6][0], aC2, 0, 0, 0);
        aC2 = __builtin_amdgcn_mfma_f32_32x32x16_bf16(al, pC2.bb[kh % 6][0], aC2, 0, 0, 0);
        pC2.roll(kh);
      }
    }
    pG1.prefetch();            // next step's G1 weights fly across tail barriers
    LGKM_BARRIER();  // B8: C2 reads of A2 done
    if (w < 4) {
#pragma unroll
      for (int j = 0; j < 16; ++j) {
        const int row = (j & 3) + 8 * (j >> 2) + 4 * hi;
        const int idx = ew(row, 256 + col2);
        const float c = tanh_(aC2[j]);
        const float hn = c + g2v[j] * (hold2[j] - c);
        const u16 hh = bf16_rne(hn);
        A2h_s[idx] = hh;                      // h2 for t+1 (and final out)
        A2l_s[idx] = bf16_rne(hn - bf16_f(hh));
      }
    }
    LGKM_BARRIER();  // loop: h2n visible
  }

  // ---- dense: out[b][o] = bd[o] + h2[b] . Wd[:,o]  (WdT fp32 in ws) ----
  {
    const float* wdT = (const float*)(ws + WTOT);   // [32][128]
    const int o = tid & 31, bq = tid >> 5;          // rows bq and bq+16
    float accA = bd[o], accB = bd[o];
#pragma unroll 4
    for (int c8 = 0; c8 < 16; ++c8) {
      const int c = c8 * 8;
      const int ia = ew(bq, 256 + c);
      const int ib = ew(bq + 16, 256 + c);
      const short8 vhA = *(const short8*)&A2h_s[ia];
      const short8 vlA = *(const short8*)&A2l_s[ia];
      const short8 vhB = *(const short8*)&A2h_s[ib];
      const short8 vlB = *(const short8*)&A2l_s[ib];
#pragma unroll
      for (int j = 0; j < 8; ++j) {
        const float wv = wdT[o * 128 + c + j];
        accA = fmaf(bf16_f((u16)vhA[j]) + bf16_f((u16)vlA[j]), wv, accA);
        accB = fmaf(bf16_f((u16)vhB[j]) + bf16_f((u16)vlB[j]), wv, accB);
      }
    }
    out[(size_t)(b0 + bq) * Fc + o] = accA;
    out[(size_t)(b0 + bq + 16) * Fc + o] = accB;
  }
}

extern "C" void kernel_launch(void* const* d_in, const int* in_sizes, int n_in,
                              void* d_out, int out_size, void* d_ws, size_t ws_size,
                              hipStream_t stream) {
  const float* frames = (const float*)d_in[0];
  const float* W1g = (const float*)d_in[1];
  const float* b1g = (const float*)d_in[2];
  const float* W1c = (const float*)d_in[3];
  const float* b1c = (const float*)d_in[4];
  const float* W2g = (const float*)d_in[5];
  const float* b2g = (const float*)d_in[6];
  const float* W2c = (const float*)d_in[7];
  const float* b2c = (const float*)d_in[8];
  const float* Wd  = (const float*)d_in[9];
  const float* bd  = (const float*)d_in[10];
  u16* ws = (u16*)d_ws;
  float* outp = (float*)d_out;

  hipLaunchKernelGGL(prep_weights, dim3((WTOT + nWdT + 255) / 256), dim3(256), 0, stream,
                     W1g, W1c, W2g, W2c, Wd, ws);
  hipLaunchKernelGGL(gru_mfma, dim3(NBLK), dim3(NTHR), 0, stream,
                     frames, ws, b1g, b1c, b2g, b2c, bd, outp);
}